// Round 2
// baseline (256.472 us; speedup 1.0000x reference)
//
#include <hip/hip_runtime.h>
#include <hip/hip_bf16.h>
#include <math.h>

#define L 2048
#define D 256

typedef __attribute__((ext_vector_type(8))) short bf16x8;
typedef __attribute__((ext_vector_type(4))) float f32x4;
typedef __attribute__((ext_vector_type(4))) int i32x4;

__device__ __forceinline__ unsigned short f2bf(float f) {
    union { float f; unsigned int u; } v; v.f = f;
    unsigned int r = v.u + 0x7FFFu + ((v.u >> 16) & 1u);   // RNE
    return (unsigned short)(r >> 16);
}

// --- transpose Wv, Wo (f32 k-major) -> bf16 n-major ---------------------
__global__ __launch_bounds__(256) void wtrans_kernel(
    const float* __restrict__ Wv, const float* __restrict__ Wo,
    unsigned short* __restrict__ Wvt, unsigned short* __restrict__ Wot) {
    int idx = blockIdx.x * 256 + threadIdx.x;       // 0..131071
    int which = idx >> 16;
    int e = idx & 65535;
    int n = e >> 8, k = e & 255;
    const float* W = which ? Wo : Wv;
    unsigned short* Wt = which ? Wot : Wvt;
    Wt[n * 256 + k] = f2bf(W[k * 256 + n]);
}

// --- LDS-free GEMM: v = value @ Wv + bv, stored TRANSPOSED bf16 Vt[b][n][j]
__global__ __launch_bounds__(256) void gemm_v_kernel(
    const float* __restrict__ A,
    const unsigned short* __restrict__ Wt,   // [256][256] bf16 n-major
    const float* __restrict__ bias,
    unsigned short* __restrict__ Vt) {
    const int wave = threadIdx.x >> 6;
    const int lane = threadIdx.x & 63;
    const int mh = wave >> 1, nh = wave & 1;
    const int lm = lane & 15, q = lane >> 4;
    const int m0 = blockIdx.x * 64;
    const int n0 = blockIdx.y * 128;

    f32x4 acc[2][4];
#pragma unroll
    for (int i = 0; i < 2; i++)
#pragma unroll
        for (int j = 0; j < 4; j++) acc[i][j] = (f32x4)(0.f);

    int arow[2];
    arow[0] = m0 + mh * 32 + lm;
    arow[1] = arow[0] + 16;
    int ncol[4];
#pragma unroll
    for (int nf = 0; nf < 4; nf++) ncol[nf] = n0 + nh * 64 + nf * 16 + lm;

    for (int k0 = 0; k0 < 256; k0 += 32) {
        int kq = k0 + q * 8;
        bf16x8 bfr[4];
#pragma unroll
        for (int nf = 0; nf < 4; nf++)
            bfr[nf] = *reinterpret_cast<const bf16x8*>(Wt + ncol[nf] * 256 + kq);
        bf16x8 afr[2];
#pragma unroll
        for (int mf = 0; mf < 2; mf++) {
            const float* ap = A + arow[mf] * 256 + kq;
            f32x4 a0 = *reinterpret_cast<const f32x4*>(ap);
            f32x4 a1 = *reinterpret_cast<const f32x4*>(ap + 4);
            bf16x8 t;
#pragma unroll
            for (int e = 0; e < 4; e++) t[e] = (short)f2bf(a0[e]);
#pragma unroll
            for (int e = 0; e < 4; e++) t[4 + e] = (short)f2bf(a1[e]);
            afr[mf] = t;
        }
#pragma unroll
        for (int mf = 0; mf < 2; mf++)
#pragma unroll
            for (int nf = 0; nf < 4; nf++)
                acc[mf][nf] = __builtin_amdgcn_mfma_f32_16x16x32_bf16(
                    afr[mf], bfr[nf], acc[mf][nf], 0, 0, 0);
    }

#pragma unroll
    for (int mf = 0; mf < 2; mf++) {
        int mrow = m0 + mh * 32 + mf * 16 + q * 4;   // rows mrow..mrow+3
#pragma unroll
        for (int nf = 0; nf < 4; nf++) {
            int n = ncol[nf];
            float bias_n = bias[n];
            int b = mrow >> 11;
            int j = mrow & 2047;
            unsigned short* dst = Vt + (size_t)b * (D * L) + (size_t)n * L + j;
            ushort4 pk;
            pk.x = f2bf(acc[mf][nf][0] + bias_n);
            pk.y = f2bf(acc[mf][nf][1] + bias_n);
            pk.z = f2bf(acc[mf][nf][2] + bias_n);
            pk.w = f2bf(acc[mf][nf][3] + bias_n);
            *reinterpret_cast<ushort4*>(dst) = pk;
        }
    }
}

// --- fused mask + exp + P@V, unnormalized (no online max), j-split x4 ---
// grid 1024: rb = blk>>2 (row block of 32), js = blk&3 (j quarter, 512 each)
// partial per block: acc[32][256] f32 + l[32]  (8224 floats)
__global__ __launch_bounds__(256) void attn_kernel(
    const float* __restrict__ atten, const float* __restrict__ mask,
    const int* __restrict__ pad, const unsigned short* __restrict__ Vt,
    float* __restrict__ part) {
    const int blk = blockIdx.x;
    const int rb = blk >> 2, js = blk & 3;
    const int b = rb >> 6;
    const int i0 = (rb & 63) * 32;
    const int tid = threadIdx.x;
    const int wave = tid >> 6, lane = tid & 63;
    const int lm = lane & 15, q = lane >> 4;
    const int r = tid >> 3;            // softmax row 0..31
    const int c0 = (tid & 7) * 8;      // j offset within 64-tile

    __shared__ __align__(16) unsigned short Plds[2][32][72];

    f32x4 acc[2][4];
#pragma unroll
    for (int i = 0; i < 2; i++)
#pragma unroll
        for (int j = 0; j < 4; j++) acc[i][j] = (f32x4)(0.f);
    float l_th = 0.f;

    const size_t rowoff = ((size_t)(b * L + i0 + r)) * L + js * 512 + c0;
    const float* at_row = atten + rowoff;
    const float* mk_row = mask + rowoff;
    const int* pd_row = pad + rowoff;
    const unsigned short* vt_b = Vt + (size_t)b * (D * L) + js * 512;

    // prefetch tile 0
    f32x4 ca0 = *reinterpret_cast<const f32x4*>(at_row);
    f32x4 ca1 = *reinterpret_cast<const f32x4*>(at_row + 4);
    f32x4 ck0 = *reinterpret_cast<const f32x4*>(mk_row);
    f32x4 ck1 = *reinterpret_cast<const f32x4*>(mk_row + 4);
    i32x4 cp0 = *reinterpret_cast<const i32x4*>(pd_row);
    i32x4 cp1 = *reinterpret_cast<const i32x4*>(pd_row + 4);

    for (int jt = 0; jt < 8; jt++) {
        const int j0 = jt * 64;
        // prefetch next tile's mask/logit streams (overlaps everything below)
        f32x4 na0, na1, nk0, nk1; i32x4 np0, np1;
        if (jt < 7) {
            const int jn = j0 + 64;
            na0 = *reinterpret_cast<const f32x4*>(at_row + jn);
            na1 = *reinterpret_cast<const f32x4*>(at_row + jn + 4);
            nk0 = *reinterpret_cast<const f32x4*>(mk_row + jn);
            nk1 = *reinterpret_cast<const f32x4*>(mk_row + jn + 4);
            np0 = *reinterpret_cast<const i32x4*>(pd_row + jn);
            np1 = *reinterpret_cast<const i32x4*>(pd_row + jn + 4);
        }
        // B fragments straight from global Vt (L2-resident)
        bf16x8 bfr[2][4];
#pragma unroll
        for (int kk = 0; kk < 2; kk++)
#pragma unroll
            for (int nf = 0; nf < 4; nf++) {
                int n = wave * 64 + nf * 16 + lm;
                bfr[kk][nf] = *reinterpret_cast<const bf16x8*>(
                    vt_b + (size_t)n * L + j0 + kk * 32 + q * 8);
            }
        // p = exp(logit) with masked -> 0 (exp(-FLT_MAX)=exp(-inf)=0)
        bf16x8 pk;
        float psum = 0.f;
#pragma unroll
        for (int e = 0; e < 4; e++) {
            float pv = (ck0[e] < 0.5f || cp0[e] == 0) ? 0.f : __expf(ca0[e]);
            float pw = (ck1[e] < 0.5f || cp1[e] == 0) ? 0.f : __expf(ca1[e]);
            psum += pv + pw;
            pk[e] = (short)f2bf(pv);
            pk[4 + e] = (short)f2bf(pw);
        }
        l_th += psum;

        const int par = jt & 1;
        *reinterpret_cast<bf16x8*>(&Plds[par][r][c0]) = pk;
        __syncthreads();

        // P @ V
#pragma unroll
        for (int kk = 0; kk < 2; kk++)
#pragma unroll
            for (int mf = 0; mf < 2; mf++) {
                bf16x8 afr = *reinterpret_cast<const bf16x8*>(
                    &Plds[par][mf * 16 + lm][kk * 32 + q * 8]);
#pragma unroll
                for (int nf = 0; nf < 4; nf++)
                    acc[mf][nf] = __builtin_amdgcn_mfma_f32_16x16x32_bf16(
                        afr, bfr[kk][nf], acc[mf][nf], 0, 0, 0);
            }
        ca0 = na0; ca1 = na1; ck0 = nk0; ck1 = nk1; cp0 = np0; cp1 = np1;
    }

    // l: reduce across the 8 threads of each row (consecutive lanes)
#pragma unroll
    for (int off = 1; off < 8; off <<= 1) l_th += __shfl_xor(l_th, off);

    float* pbase = part + (size_t)blk * 8224;
#pragma unroll
    for (int mf = 0; mf < 2; mf++)
#pragma unroll
        for (int nf = 0; nf < 4; nf++) {
            int n = wave * 64 + nf * 16 + lm;
#pragma unroll
            for (int rg = 0; rg < 4; rg++)
                pbase[(mf * 16 + q * 4 + rg) * 256 + n] = acc[mf][nf][rg];
        }
    if ((tid & 7) == 0) pbase[8192 + r] = l_th;
}

// --- combine 4 j-partials, normalize, then fused GEMM with Wo -----------
// one block per 32-row tile; out rows rb*32..rb*32+31
__global__ __launch_bounds__(256) void combine_gemm_kernel(
    const float* __restrict__ part, const unsigned short* __restrict__ Wot,
    const float* __restrict__ bo, float* __restrict__ out) {
    const int rb = blockIdx.x;        // 0..255
    const int tid = threadIdx.x;
    const int wave = tid >> 6, lane = tid & 63;
    const int lm = lane & 15, q = lane >> 4;
    const int r = tid >> 3;           // 0..31
    const int n0 = (tid & 7) * 32;

    __shared__ __align__(16) unsigned short Alds[32][264];

    const float* pb = part + (size_t)(rb * 4) * 8224;
    float l = pb[8192 + r] + pb[8224 + 8192 + r] +
              pb[2 * 8224 + 8192 + r] + pb[3 * 8224 + 8192 + r];
    float inv = 1.f / l;
#pragma unroll
    for (int e = 0; e < 32; e += 4) {
        f32x4 s = (f32x4)(0.f);
#pragma unroll
        for (int js = 0; js < 4; js++)
            s += *reinterpret_cast<const f32x4*>(pb + js * 8224 + r * 256 + n0 + e);
        s *= inv;
        ushort4 pk;
        pk.x = f2bf(s[0]); pk.y = f2bf(s[1]); pk.z = f2bf(s[2]); pk.w = f2bf(s[3]);
        *reinterpret_cast<ushort4*>(&Alds[r][n0 + e]) = pk;
    }
    __syncthreads();

    // 32x256 @ 256x256 GEMM: A from LDS, B = Wot (n-major, global)
    f32x4 acc[2][4];
#pragma unroll
    for (int i = 0; i < 2; i++)
#pragma unroll
        for (int j = 0; j < 4; j++) acc[i][j] = (f32x4)(0.f);
    int ncol[4];
#pragma unroll
    for (int nf = 0; nf < 4; nf++) ncol[nf] = wave * 64 + nf * 16 + lm;

    for (int kk = 0; kk < 8; kk++) {
        int kq = kk * 32 + q * 8;
        bf16x8 bfr[4];
#pragma unroll
        for (int nf = 0; nf < 4; nf++)
            bfr[nf] = *reinterpret_cast<const bf16x8*>(Wot + ncol[nf] * 256 + kq);
#pragma unroll
        for (int mf = 0; mf < 2; mf++) {
            bf16x8 afr = *reinterpret_cast<const bf16x8*>(&Alds[mf * 16 + lm][kq]);
#pragma unroll
            for (int nf = 0; nf < 4; nf++)
                acc[mf][nf] = __builtin_amdgcn_mfma_f32_16x16x32_bf16(
                    afr, bfr[nf], acc[mf][nf], 0, 0, 0);
        }
    }

#pragma unroll
    for (int mf = 0; mf < 2; mf++) {
        int mrow = rb * 32 + mf * 16 + q * 4;
#pragma unroll
        for (int nf = 0; nf < 4; nf++) {
            int n = ncol[nf];
            float bn = bo[n];
#pragma unroll
            for (int rg = 0; rg < 4; rg++)
                out[(size_t)(mrow + rg) * 256 + n] = acc[mf][nf][rg] + bn;
        }
    }
}

extern "C" void kernel_launch(void* const* d_in, const int* in_sizes, int n_in,
                              void* d_out, int out_size, void* d_ws, size_t ws_size,
                              hipStream_t stream) {
    (void)in_sizes; (void)n_in; (void)out_size; (void)ws_size;
    const float* atten = (const float*)d_in[0];
    const float* value = (const float*)d_in[1];
    const float* mask  = (const float*)d_in[2];
    const int*   pad   = (const int*)d_in[3];
    const float* Wv    = (const float*)d_in[4];
    const float* bv    = (const float*)d_in[5];
    const float* Wo    = (const float*)d_in[6];
    const float* bo    = (const float*)d_in[7];
    float* out = (float*)d_out;

    char* ws = (char*)d_ws;
    unsigned short* Vt  = (unsigned short*)(ws);              // 4 MB  bf16 [B][D][L]
    unsigned short* Wvt = (unsigned short*)(ws + 4194304);    // 128 KB
    unsigned short* Wot = (unsigned short*)(ws + 4325376);    // 128 KB
    float* part = (float*)(ws + 4456448);                     // 1024 * 8224 * 4 B

    wtrans_kernel<<<512, 256, 0, stream>>>(Wv, Wo, Wvt, Wot);
    gemm_v_kernel<<<dim3(128, 2), 256, 0, stream>>>(value, Wvt, bv, Vt);
    attn_kernel<<<1024, 256, 0, stream>>>(atten, mask, pad, Vt, part);
    combine_gemm_kernel<<<256, 256, 0, stream>>>(part, Wot, bo, out);
}